// Round 11
// baseline (785.976 us; speedup 1.0000x reference)
//
#include <hip/hip_runtime.h>

#define NN 100000
#define NE 1600000
#define NG 2048
#define IN_DIM 32
#define PEP_DIM 768
#define H 64
#define BN_EPS 1e-5f
#define SCAN_BLK 1024
#define NB ((NN + SCAN_BLK - 1) / SCAN_BLK)   // 98 blocks
#define CONV_W 16   // waves (=nodes) per k_conv block
#define DEPTH 8     // forced in-flight gathers per wave

typedef unsigned int uint;
typedef unsigned short ushort;

__device__ __forceinline__ float bf2f(uint u) {
    return __uint_as_float((u & 0xFFFFu) << 16);
}
__device__ __forceinline__ uint f2bf(float x) {
    uint b = __float_as_uint(x);
    return (b + 0x7FFFu + ((b >> 16) & 1u)) >> 16;   // RNE
}

// ---------------- degree count: deg[dst]++ ----------------
__global__ void k_degree(const int* __restrict__ ei, int* __restrict__ deg) {
    int e = blockIdx.x * 256 + threadIdx.x;
    if (e < NE) atomicAdd(&deg[ei[NE + e]], 1);
}

// ---------------- scan stage 1: per-block sums ----------------
__global__ __launch_bounds__(256) void k_scan1(const int* __restrict__ deg, int* __restrict__ bsum) {
    __shared__ int red[64];
    int base = blockIdx.x * SCAN_BLK + threadIdx.x * 4;
    int s = 0;
    for (int j = 0; j < 4; j++) {
        int i = base + j;
        if (i < NN) s += deg[i];
    }
    for (int off = 32; off > 0; off >>= 1) s += __shfl_down(s, off, 64);
    int wave = threadIdx.x >> 6;
    if ((threadIdx.x & 63) == 0) red[wave] = s;
    __syncthreads();
    if (threadIdx.x == 0) bsum[blockIdx.x] = red[0] + red[1] + red[2] + red[3];
}

// ---------------- scan stage 2 ----------------
__global__ void k_scan2(int* __restrict__ bsum, int* __restrict__ row_start) {
    if (threadIdx.x == 0) {
        int run = 0;
        for (int b = 0; b < NB; b++) { int t = bsum[b]; bsum[b] = run; run += t; }
        row_start[NN] = NE;
    }
}

// ---------------- scan stage 3 (fills row_start and cursor) ----------------
__global__ __launch_bounds__(256) void k_scan3(const int* __restrict__ deg, const int* __restrict__ bsum,
                                               int* __restrict__ row_start, int* __restrict__ cursor) {
    __shared__ int s[256];
    int base = blockIdx.x * SCAN_BLK + threadIdx.x * 4;
    int v[4];
    int tot = 0;
    for (int j = 0; j < 4; j++) {
        int i = base + j;
        v[j] = (i < NN) ? deg[i] : 0;
        tot += v[j];
    }
    s[threadIdx.x] = tot;
    __syncthreads();
    for (int off = 1; off < 256; off <<= 1) {
        int x = (threadIdx.x >= off) ? s[threadIdx.x - off] : 0;
        __syncthreads();
        s[threadIdx.x] += x;
        __syncthreads();
    }
    int excl = s[threadIdx.x] - tot + bsum[blockIdx.x];
    for (int j = 0; j < 4; j++) {
        int i = base + j;
        if (i < NN) { row_start[i] = excl; cursor[i] = excl; excl += v[j]; }
    }
}

// ---------------- fill CSR: csr[pos] = {src, packed bf16 attrs} ----------------
__global__ void k_fill(const int* __restrict__ ei, const float* __restrict__ ea,
                       int* __restrict__ cursor, int2* __restrict__ csr) {
    int e = blockIdx.x * 256 + threadIdx.x;
    if (e >= NE) return;
    int src = ei[e];
    int dst = ei[NE + e];
    float2 a = *(const float2*)(ea + e * 2);
    int pos = atomicAdd(&cursor[dst], 1);
    int2 v;
    v.x = src;
    v.y = (int)(f2bf(a.x) | (f2bf(a.y) << 16));
    csr[pos] = v;
}

// ---------------- graph boundaries from sorted batch ----------------
__global__ void k_gstart(const int* __restrict__ batch, int* __restrict__ gstart) {
    int i = blockIdx.x * 256 + threadIdx.x;
    if (i >= NN) return;
    int b = batch[i];
    int p = (i == 0) ? -1 : batch[i - 1];
    for (int g = p + 1; g <= b; g++) gstart[g] = i;
    if (i == NN - 1) {
        for (int g = b + 1; g <= NG; g++) gstart[g] = NN;
    }
}

// ---------------- h0 = x @ in_w + in_b (bf16 out) ----------------
__global__ void k_init_h(const float* __restrict__ x, const float* __restrict__ w,
                         const float* __restrict__ b, ushort* __restrict__ h) {
    int t = blockIdx.x * 256 + threadIdx.x;
    int node = t >> 4;
    if (node >= NN) return;
    int c4 = (t & 15) * 4;
    float4 acc = *(const float4*)(b + c4);
    const float* xr = x + node * IN_DIM;
    for (int k = 0; k < IN_DIM; k++) {
        float xv = xr[k];
        float4 wv = *(const float4*)(w + k * H + c4);
        acc.x += xv * wv.x; acc.y += xv * wv.y;
        acc.z += xv * wv.z; acc.w += xv * wv.w;
    }
    uint2 o;
    o.x = f2bf(acc.x) | (f2bf(acc.y) << 16);
    o.y = f2bf(acc.z) | (f2bf(acc.w) << 16);
    *(uint2*)(h + (size_t)node * H + c4) = o;
}

// ---------------- fused GINE layer: gather + MLP + BN + relu ----------------
// One wave per node. Gathers are issued as DEPTH inline-asm
// global_load_ushort (saddr + 32-bit voffset) with "=v" outputs: the register
// allocator MUST keep DEPTH dests+addrs live -> DEPTH loads in flight per
// wave. r8/r10 evidence: at source level the scheduler re-rolled every
// unroll to VGPR 32-40 and serialized gathers (~10 lines/CU in flight,
// 52 cy/line vs ~500 cy latency). One s_waitcnt vmcnt(0) + sched_barrier(0)
// (hipcc hoists consumers past asm waitcnt otherwise - guide rule 18).
// Tail handled by clamp+mask, no serial epilogue. No __syncthreads
// (wave-private LDS rows).
__global__ __launch_bounds__(1024, 4) void k_conv(
    const ushort* __restrict__ h_in, ushort* __restrict__ h_out,
    const int2* __restrict__ csr, const int* __restrict__ row_start,
    const float* __restrict__ ew, const float* __restrict__ eb,
    const float* __restrict__ W1, const float* __restrict__ b1,
    const float* __restrict__ W2, const float* __restrict__ b2,
    const float* __restrict__ bnw, const float* __restrict__ bnb,
    const float* __restrict__ bnm, const float* __restrict__ bnv) {
    __shared__ float zs[CONV_W][H];
    __shared__ float ts[CONV_W][H];
    int w = threadIdx.x >> 6;
    int c = threadIdx.x & 63;
    int node = blockIdx.x * CONV_W + w;
    float ew0 = ew[c], ew1 = ew[H + c], ebc = eb[c];
    int rs = __builtin_amdgcn_readfirstlane(row_start[node]);
    int re = __builtin_amdgcn_readfirstlane(row_start[node + 1]);
    float acc = 0.f;
    int c2 = c * 2;
    for (int j = rs; j < re; j += DEPTH) {
        int2 v[DEPTH];
        float m[DEPTH];
        uint voff[DEPTH];
        uint hv[DEPTH];
        #pragma unroll
        for (int t = 0; t < DEPTH; t++) {
            int idx = j + t;
            m[t] = (idx < re) ? 1.f : 0.f;
            idx = min(idx, re - 1);
            v[t] = csr[idx];
            voff[t] = (uint)v[t].x * (H * 2) + c2;
        }
        #pragma unroll
        for (int t = 0; t < DEPTH; t++) {
            asm volatile("global_load_ushort %0, %1, %2"
                         : "=v"(hv[t]) : "v"(voff[t]), "s"(h_in));
        }
        asm volatile("s_waitcnt vmcnt(0)" ::: "memory");
        __builtin_amdgcn_sched_barrier(0);
        #pragma unroll
        for (int t = 0; t < DEPTH; t++) {
            uint a = (uint)v[t].y;
            acc += m[t] * fmaxf(bf2f(hv[t]) +
                                fmaf(bf2f(a), ew0, fmaf(bf2f(a >> 16), ew1, ebc)), 0.f);
        }
    }
    float z = bf2f(h_in[(size_t)node * H + c]) + acc;
    zs[w][c] = z;
    float a1 = b1[c];
    for (int k = 0; k < H; k += 4) {
        float4 zv = *(const float4*)&zs[w][k];
        a1 = fmaf(zv.x, W1[(k + 0) * H + c], a1);
        a1 = fmaf(zv.y, W1[(k + 1) * H + c], a1);
        a1 = fmaf(zv.z, W1[(k + 2) * H + c], a1);
        a1 = fmaf(zv.w, W1[(k + 3) * H + c], a1);
    }
    ts[w][c] = fmaxf(a1, 0.f);
    float a2 = b2[c];
    for (int k = 0; k < H; k += 4) {
        float4 tv = *(const float4*)&ts[w][k];
        a2 = fmaf(tv.x, W2[(k + 0) * H + c], a2);
        a2 = fmaf(tv.y, W2[(k + 1) * H + c], a2);
        a2 = fmaf(tv.z, W2[(k + 2) * H + c], a2);
        a2 = fmaf(tv.w, W2[(k + 3) * H + c], a2);
    }
    float scale = bnw[c] * rsqrtf(bnv[c] + BN_EPS);
    float hn = fmaxf((a2 - bnm[c]) * scale + bnb[c], 0.f);
    // pack 2 channels -> 1 dword store by even lanes
    uint me = f2bf(hn);
    uint nb = __shfl_down(me, 1, 64);
    if ((c & 1) == 0) {
        *(uint*)(h_out + (size_t)node * H + c) = me | (nb << 16);
    }
}

// ---------------- fused pooling + vn MLP + h += vn (addvn fused) ----------
// one wave per graph; batch sorted so graph = contiguous node range.
__global__ __launch_bounds__(256) void k_poolvn(ushort* __restrict__ h,
                                                const int* __restrict__ gstart,
                                                float* __restrict__ pooled,
                                                const float* __restrict__ w1, const float* __restrict__ b1,
                                                const float* __restrict__ w2, const float* __restrict__ b2,
                                                float* __restrict__ vn, int do_vn) {
    __shared__ float ps[4][H];
    __shared__ float ts[4][H];
    int w = threadIdx.x >> 6, c = threadIdx.x & 63;
    int g = blockIdx.x * 4 + w;
    int s = __builtin_amdgcn_readfirstlane(gstart[g]);
    int e = __builtin_amdgcn_readfirstlane(gstart[g + 1]);
    float acc = 0.f;
    int n = s;
    for (; n + 4 <= e; n += 4) {
        float x0 = bf2f(h[(size_t)(n + 0) * H + c]);
        float x1 = bf2f(h[(size_t)(n + 1) * H + c]);
        float x2 = bf2f(h[(size_t)(n + 2) * H + c]);
        float x3 = bf2f(h[(size_t)(n + 3) * H + c]);
        acc += x0; acc += x1; acc += x2; acc += x3;
    }
    for (; n < e; n++) acc += bf2f(h[(size_t)n * H + c]);
    pooled[(size_t)g * H + c] = acc;
    if (!do_vn) return;
    ps[w][c] = acc;
    float a1 = b1[c];
    for (int k = 0; k < H; k += 4) {
        float4 pv = *(const float4*)&ps[w][k];
        a1 = fmaf(pv.x, w1[(k + 0) * H + c], a1);
        a1 = fmaf(pv.y, w1[(k + 1) * H + c], a1);
        a1 = fmaf(pv.z, w1[(k + 2) * H + c], a1);
        a1 = fmaf(pv.w, w1[(k + 3) * H + c], a1);
    }
    ts[w][c] = fmaxf(a1, 0.f);
    float a2 = b2[c];
    for (int k = 0; k < H; k += 4) {
        float4 tv = *(const float4*)&ts[w][k];
        a2 = fmaf(tv.x, w2[(k + 0) * H + c], a2);
        a2 = fmaf(tv.y, w2[(k + 1) * H + c], a2);
        a2 = fmaf(tv.z, w2[(k + 2) * H + c], a2);
        a2 = fmaf(tv.w, w2[(k + 3) * H + c], a2);
    }
    float vnew = vn[(size_t)g * H + c] + a2;
    vn[(size_t)g * H + c] = vnew;
    // ---- fused addvn: h[n] += vnew for all nodes n of graph g ----
    ps[w][c] = vnew;
    float vlo = ps[w][(c & 31) * 2 + 0];
    float vhi = ps[w][(c & 31) * 2 + 1];
    int ch2 = (c & 31) * 2;
    for (n = s; n + 2 <= e; n += 2) {
        size_t off = (size_t)(n + (c >> 5)) * H + ch2;
        uint u = *(uint*)(h + off);
        float lo = bf2f(u) + vlo;
        float hi = bf2f(u >> 16) + vhi;
        *(uint*)(h + off) = f2bf(lo) | (f2bf(hi) << 16);
    }
    if (n < e && c < 32) {   // odd tail
        size_t off = (size_t)n * H + ch2;
        uint u = *(uint*)(h + off);
        float lo = bf2f(u) + vlo;
        float hi = bf2f(u >> 16) + vhi;
        *(uint*)(h + off) = f2bf(lo) | (f2bf(hi) << 16);
    }
}

// ---------------- final: mean pool, pep MLP, classifier ----------------
__global__ __launch_bounds__(256) void k_final(const float* __restrict__ pooled,
                                               const int* __restrict__ gstart,
                                               const float* __restrict__ pep,
                                               const float* __restrict__ pw, const float* __restrict__ pb,
                                               const float* __restrict__ cw1, const float* __restrict__ cb1,
                                               const float* __restrict__ cw2, const float* __restrict__ cb2,
                                               float* __restrict__ out) {
    __shared__ float red[4][H];
    __shared__ float fused[2 * H];
    int g = blockIdx.x;
    int lane = threadIdx.x & 63;
    int part = threadIdx.x >> 6;
    const float* pr = pep + (size_t)g * PEP_DIM;
    float acc = 0.0f;
    int k0 = part * (PEP_DIM / 4);
    for (int k = k0; k < k0 + PEP_DIM / 4; k++) {
        acc += pr[k] * pw[k * H + lane];
    }
    red[part][lane] = acc;
    __syncthreads();
    if (part == 0) {
        float s = red[0][lane] + red[1][lane] + red[2][lane] + red[3][lane] + pb[lane];
        fused[H + lane] = fmaxf(s, 0.0f);
        float c = (float)(gstart[g + 1] - gstart[g]);
        float invc = 1.0f / fmaxf(c, 1.0f);
        fused[lane] = pooled[(size_t)g * H + lane] * invc;
    }
    __syncthreads();
    if (part == 0) {
        float a = cb1[lane];
        for (int k = 0; k < 2 * H; k++) a += fused[k] * cw1[k * H + lane];
        float t = fmaxf(a, 0.0f);
        float v = t * cw2[lane];
        for (int off = 32; off > 0; off >>= 1) v += __shfl_down(v, off, 64);
        if (lane == 0) out[g] = v + cb2[0];
    }
}

extern "C" void kernel_launch(void* const* d_in, const int* in_sizes, int n_in,
                              void* d_out, int out_size, void* d_ws, size_t ws_size,
                              hipStream_t stream) {
    const float* x        = (const float*)d_in[0];
    const int*   ei       = (const int*)d_in[1];
    const int*   batch    = (const int*)d_in[2];
    const float* ea       = (const float*)d_in[3];
    const float* pep      = (const float*)d_in[4];
    const float* in_w     = (const float*)d_in[5];
    const float* in_b     = (const float*)d_in[6];
    const float* e_w      = (const float*)d_in[7];
    const float* e_b      = (const float*)d_in[8];
    const float* conv_w1  = (const float*)d_in[9];
    const float* conv_b1  = (const float*)d_in[10];
    const float* conv_w2  = (const float*)d_in[11];
    const float* conv_b2  = (const float*)d_in[12];
    const float* bn_w     = (const float*)d_in[13];
    const float* bn_b     = (const float*)d_in[14];
    const float* bn_mean  = (const float*)d_in[15];
    const float* bn_var   = (const float*)d_in[16];
    const float* vn_w1    = (const float*)d_in[17];
    const float* vn_b1    = (const float*)d_in[18];
    const float* vn_w2    = (const float*)d_in[19];
    const float* vn_b2    = (const float*)d_in[20];
    const float* pep_w    = (const float*)d_in[21];
    const float* pep_b    = (const float*)d_in[22];
    const float* cls_w1   = (const float*)d_in[23];
    const float* cls_b1   = (const float*)d_in[24];
    const float* cls_w2   = (const float*)d_in[25];
    const float* cls_b2   = (const float*)d_in[26];
    float* out = (float*)d_out;

    // ---- workspace layout ----
    ushort* h_a   = (ushort*)d_ws;                    // NN*H bf16
    ushort* h_b   = h_a + (size_t)NN * H;             // NN*H bf16
    float* pooled = (float*)(h_b + (size_t)NN * H);   // NG*H
    float* vn     = pooled + (size_t)NG * H;          // NG*H
    int2*  csr    = (int2*)(vn + (size_t)NG * H);     // NE (8B each)
    int* row_start = (int*)(csr + (size_t)NE);        // NN+16
    int* cursor    = row_start + NN + 16;             // NN+16
    int* gstart    = cursor + NN + 16;                // NG+16
    int* bsum      = gstart + NG + 16;                // NB (<=128)

    // ---- build CSR (once; reused by all 3 layers) ----
    hipMemsetAsync(cursor, 0, (size_t)NN * sizeof(int), stream);
    k_degree<<<(NE + 255) / 256, 256, 0, stream>>>(ei, cursor);
    k_scan1<<<NB, 256, 0, stream>>>(cursor, bsum);
    k_scan2<<<1, 64, 0, stream>>>(bsum, row_start);
    k_scan3<<<NB, 256, 0, stream>>>(cursor, bsum, row_start, cursor);
    k_fill<<<(NE + 255) / 256, 256, 0, stream>>>(ei, ea, cursor, csr);
    k_gstart<<<(NN + 255) / 256, 256, 0, stream>>>(batch, gstart);

    // ---- init ----
    k_init_h<<<NN * 16 / 256, 256, 0, stream>>>(x, in_w, in_b, h_a);
    hipMemsetAsync(vn, 0, (size_t)NG * H * sizeof(float), stream);

    ushort* hc = h_a;
    ushort* hn = h_b;
    for (int i = 0; i < 3; i++) {
        k_conv<<<NN / CONV_W, 1024, 0, stream>>>(hc, hn, csr, row_start,
                                           e_w, e_b,
                                           conv_w1 + i * H * H, conv_b1 + i * H,
                                           conv_w2 + i * H * H, conv_b2 + i * H,
                                           bn_w + i * H, bn_b + i * H,
                                           bn_mean + i * H, bn_var + i * H);
        ushort* t = hc; hc = hn; hn = t;   // hc now holds layer output
        k_poolvn<<<NG / 4, 256, 0, stream>>>(hc, gstart, pooled,
                                             vn_w1, vn_b1, vn_w2, vn_b2, vn,
                                             (i < 2) ? 1 : 0);
    }

    k_final<<<NG, 256, 0, stream>>>(pooled, gstart, pep, pep_w, pep_b,
                                    cls_w1, cls_b1, cls_w2, cls_b2, out);
}

// Round 12
// 472.641 us; speedup vs baseline: 1.6629x; 1.6629x over previous
//
#include <hip/hip_runtime.h>

#define NN 100000
#define NE 1600000
#define NG 2048
#define IN_DIM 32
#define PEP_DIM 768
#define H 64
#define BN_EPS 1e-5f
#define SCAN_BLK 1024
#define NB ((NN + SCAN_BLK - 1) / SCAN_BLK)   // 98 blocks
#define CONV_W 16   // waves (=nodes) per k_gather block

typedef unsigned int uint;
typedef unsigned short ushort;
typedef __attribute__((ext_vector_type(8))) __bf16 bf16x8;
typedef __attribute__((ext_vector_type(4))) float f32x4;

__device__ __forceinline__ float bf2f(uint u) {
    return __uint_as_float((u & 0xFFFFu) << 16);
}
__device__ __forceinline__ uint f2bf(float x) {
    uint b = __float_as_uint(x);
    return (b + 0x7FFFu + ((b >> 16) & 1u)) >> 16;   // RNE
}

// ---------------- degree count: deg[dst]++ ----------------
__global__ void k_degree(const int* __restrict__ ei, int* __restrict__ deg) {
    int e = blockIdx.x * 256 + threadIdx.x;
    if (e < NE) atomicAdd(&deg[ei[NE + e]], 1);
}

// ---------------- scan stage 1: per-block sums ----------------
__global__ __launch_bounds__(256) void k_scan1(const int* __restrict__ deg, int* __restrict__ bsum) {
    __shared__ int red[64];
    int base = blockIdx.x * SCAN_BLK + threadIdx.x * 4;
    int s = 0;
    for (int j = 0; j < 4; j++) {
        int i = base + j;
        if (i < NN) s += deg[i];
    }
    for (int off = 32; off > 0; off >>= 1) s += __shfl_down(s, off, 64);
    int wave = threadIdx.x >> 6;
    if ((threadIdx.x & 63) == 0) red[wave] = s;
    __syncthreads();
    if (threadIdx.x == 0) bsum[blockIdx.x] = red[0] + red[1] + red[2] + red[3];
}

// ---------------- scan stage 2 ----------------
__global__ void k_scan2(int* __restrict__ bsum, int* __restrict__ row_start) {
    if (threadIdx.x == 0) {
        int run = 0;
        for (int b = 0; b < NB; b++) { int t = bsum[b]; bsum[b] = run; run += t; }
        row_start[NN] = NE;
    }
}

// ---------------- scan stage 3 (fills row_start and cursor) ----------------
__global__ __launch_bounds__(256) void k_scan3(const int* __restrict__ deg, const int* __restrict__ bsum,
                                               int* __restrict__ row_start, int* __restrict__ cursor) {
    __shared__ int s[256];
    int base = blockIdx.x * SCAN_BLK + threadIdx.x * 4;
    int v[4];
    int tot = 0;
    for (int j = 0; j < 4; j++) {
        int i = base + j;
        v[j] = (i < NN) ? deg[i] : 0;
        tot += v[j];
    }
    s[threadIdx.x] = tot;
    __syncthreads();
    for (int off = 1; off < 256; off <<= 1) {
        int x = (threadIdx.x >= off) ? s[threadIdx.x - off] : 0;
        __syncthreads();
        s[threadIdx.x] += x;
        __syncthreads();
    }
    int excl = s[threadIdx.x] - tot + bsum[blockIdx.x];
    for (int j = 0; j < 4; j++) {
        int i = base + j;
        if (i < NN) { row_start[i] = excl; cursor[i] = excl; excl += v[j]; }
    }
}

// ---------------- fill CSR: csr[pos] = {src, packed bf16 attrs} ----------------
__global__ void k_fill(const int* __restrict__ ei, const float* __restrict__ ea,
                       int* __restrict__ cursor, int2* __restrict__ csr) {
    int e = blockIdx.x * 256 + threadIdx.x;
    if (e >= NE) return;
    int src = ei[e];
    int dst = ei[NE + e];
    float2 a = *(const float2*)(ea + e * 2);
    int pos = atomicAdd(&cursor[dst], 1);
    int2 v;
    v.x = src;
    v.y = (int)(f2bf(a.x) | (f2bf(a.y) << 16));
    csr[pos] = v;
}

// ---------------- graph boundaries from sorted batch ----------------
__global__ void k_gstart(const int* __restrict__ batch, int* __restrict__ gstart) {
    int i = blockIdx.x * 256 + threadIdx.x;
    if (i >= NN) return;
    int b = batch[i];
    int p = (i == 0) ? -1 : batch[i - 1];
    for (int g = p + 1; g <= b; g++) gstart[g] = i;
    if (i == NN - 1) {
        for (int g = b + 1; g <= NG; g++) gstart[g] = NN;
    }
}

// ---------------- h0 = x @ in_w + in_b (bf16 out) ----------------
__global__ void k_init_h(const float* __restrict__ x, const float* __restrict__ w,
                         const float* __restrict__ b, ushort* __restrict__ h) {
    int t = blockIdx.x * 256 + threadIdx.x;
    int node = t >> 4;
    if (node >= NN) return;
    int c4 = (t & 15) * 4;
    float4 acc = *(const float4*)(b + c4);
    const float* xr = x + node * IN_DIM;
    for (int k = 0; k < IN_DIM; k++) {
        float xv = xr[k];
        float4 wv = *(const float4*)(w + k * H + c4);
        acc.x += xv * wv.x; acc.y += xv * wv.y;
        acc.z += xv * wv.z; acc.w += xv * wv.w;
    }
    uint2 o;
    o.x = f2bf(acc.x) | (f2bf(acc.y) << 16);
    o.y = f2bf(acc.z) | (f2bf(acc.w) << 16);
    *(uint2*)(h + (size_t)node * H + c4) = o;
}

// ---------------- pack conv weights into MFMA B-fragment layout ----------
// layout: [layer 3][stage 2][kstep 2][ctile 4][lane 64][j 8] bf16
// element: W[k][c], k = ks*32 + (lane>>4)*8 + j, c = ct*16 + (lane&15)
__global__ void k_prep(const float* __restrict__ w1, const float* __restrict__ w2,
                       ushort* __restrict__ wp) {
    int t = blockIdx.x * 256 + threadIdx.x;
    if (t >= 3 * 8192) return;
    int j = t & 7;
    int lane = (t >> 3) & 63;
    int ct = (t >> 9) & 3;
    int ks = (t >> 11) & 1;
    int st = (t >> 12) & 1;
    int ly = t >> 13;
    int k = ks * 32 + (lane >> 4) * 8 + j;
    int c = ct * 16 + (lane & 15);
    const float* src = (st == 0) ? w1 : w2;
    wp[t] = (ushort)f2bf(src[ly * H * H + k * H + c]);
}

// ---------------- gather only: z = h_self + sum relu(h[src]+e) ----------
// one wave per node, lane = channel. No LDS, no MLP (r12 split: the fused
// kernel's MLP LDS broadcasts consumed ~50% of CU cycles on the LDS pipe).
__global__ __launch_bounds__(1024, 4) void k_gather(
    const ushort* __restrict__ h_in, ushort* __restrict__ z,
    const int2* __restrict__ csr, const int* __restrict__ row_start,
    const float* __restrict__ ew, const float* __restrict__ eb) {
    int w = threadIdx.x >> 6;
    int c = threadIdx.x & 63;
    int node = blockIdx.x * CONV_W + w;
    float ew0 = ew[c], ew1 = ew[H + c], ebc = eb[c];
    int rs = __builtin_amdgcn_readfirstlane(row_start[node]);
    int re = __builtin_amdgcn_readfirstlane(row_start[node + 1]);
    float acc = 0.f;
    int j = rs;
    for (; j + 16 <= re; j += 16) {
        int2 v[16];
        #pragma unroll
        for (int t = 0; t < 16; t++) v[t] = csr[j + t];
        float hh[16];
        #pragma unroll
        for (int t = 0; t < 16; t++) hh[t] = bf2f(h_in[(size_t)v[t].x * H + c]);
        #pragma unroll
        for (int t = 0; t < 16; t++)
            acc += fmaxf(hh[t] + fmaf(bf2f(v[t].y), ew0, fmaf(bf2f((uint)v[t].y >> 16), ew1, ebc)), 0.f);
    }
    for (; j + 4 <= re; j += 4) {
        int2 v[4];
        #pragma unroll
        for (int t = 0; t < 4; t++) v[t] = csr[j + t];
        float hh[4];
        #pragma unroll
        for (int t = 0; t < 4; t++) hh[t] = bf2f(h_in[(size_t)v[t].x * H + c]);
        #pragma unroll
        for (int t = 0; t < 4; t++)
            acc += fmaxf(hh[t] + fmaf(bf2f(v[t].y), ew0, fmaf(bf2f((uint)v[t].y >> 16), ew1, ebc)), 0.f);
    }
    for (; j < re; j++) {
        int2 v = csr[j];
        float hs = bf2f(h_in[(size_t)v.x * H + c]);
        acc += fmaxf(hs + fmaf(bf2f(v.y), ew0, fmaf(bf2f((uint)v.y >> 16), ew1, ebc)), 0.f);
    }
    float zv = bf2f(h_in[(size_t)node * H + c]) + acc;
    uint me = f2bf(zv);
    uint nb2 = __shfl_down(me, 1, 64);
    if ((c & 1) == 0) {
        *(uint*)(z + (size_t)node * H + c) = me | (nb2 << 16);
    }
}

// ---------------- MFMA MLP: h_out = relu(BN(relu(z@W1+b1)@W2+b2)) --------
// 16 nodes per wave, 4 waves/block. mfma_f32_16x16x32_bf16:
// A: row=lane&15, k=(lane>>4)*8+j (contiguous-k bf16x8 — m92/m97 pattern)
// C/D: col=lane&15, row=(lane>>4)*4+reg (m89 verified)
// GEMM1->GEMM2 handoff via wave-private LDS tile, rows padded to 72 shorts
// (144 B: 16B-aligned for b128, banks spread). No __syncthreads needed.
__global__ __launch_bounds__(256, 4) void k_mlp(
    const ushort* __restrict__ z, ushort* __restrict__ h_out,
    const ushort* __restrict__ wp,
    const float* __restrict__ b1, const float* __restrict__ b2,
    const float* __restrict__ bnw, const float* __restrict__ bnb,
    const float* __restrict__ bnm, const float* __restrict__ bnv) {
    __shared__ ushort ts[4][16][72];
    int w = threadIdx.x >> 6;
    int l = threadIdx.x & 63;
    int nb = blockIdx.x * 64 + w * 16;
    if (nb >= NN) return;
    int r = l & 15;
    int kg = l >> 4;
    const ushort* zr = z + (size_t)(nb + r) * H + kg * 8;
    bf16x8 A0 = *(const bf16x8*)(zr);
    bf16x8 A1 = *(const bf16x8*)(zr + 32);
    // GEMM1
    f32x4 acc[4];
    #pragma unroll
    for (int ct = 0; ct < 4; ct++) {
        bf16x8 B0 = *(const bf16x8*)(wp + (0 * 4 + ct) * 512 + l * 8);
        bf16x8 B1 = *(const bf16x8*)(wp + (1 * 4 + ct) * 512 + l * 8);
        f32x4 a = {0.f, 0.f, 0.f, 0.f};
        a = __builtin_amdgcn_mfma_f32_16x16x32_bf16(A0, B0, a, 0, 0, 0);
        a = __builtin_amdgcn_mfma_f32_16x16x32_bf16(A1, B1, a, 0, 0, 0);
        acc[ct] = a;
    }
    // t = relu(acc + b1) -> LDS (bf16, A-layout for GEMM2)
    #pragma unroll
    for (int ct = 0; ct < 4; ct++) {
        int col = ct * 16 + r;
        float bb = b1[col];
        #pragma unroll
        for (int q = 0; q < 4; q++) {
            float tv = fmaxf(acc[ct][q] + bb, 0.f);
            ts[w][kg * 4 + q][col] = (ushort)f2bf(tv);
        }
    }
    bf16x8 T0 = *(const bf16x8*)(&ts[w][r][kg * 8]);
    bf16x8 T1 = *(const bf16x8*)(&ts[w][r][32 + kg * 8]);
    // GEMM2
    f32x4 acc2[4];
    #pragma unroll
    for (int ct = 0; ct < 4; ct++) {
        bf16x8 B0 = *(const bf16x8*)(wp + 4096 + (0 * 4 + ct) * 512 + l * 8);
        bf16x8 B1 = *(const bf16x8*)(wp + 4096 + (1 * 4 + ct) * 512 + l * 8);
        f32x4 a = {0.f, 0.f, 0.f, 0.f};
        a = __builtin_amdgcn_mfma_f32_16x16x32_bf16(T0, B0, a, 0, 0, 0);
        a = __builtin_amdgcn_mfma_f32_16x16x32_bf16(T1, B1, a, 0, 0, 0);
        acc2[ct] = a;
    }
    // BN + relu -> LDS (bf16)
    #pragma unroll
    for (int ct = 0; ct < 4; ct++) {
        int col = ct * 16 + r;
        float bb2 = b2[col];
        float mean = bnm[col];
        float sc = bnw[col] * rsqrtf(bnv[col] + BN_EPS);
        float bo = bnb[col];
        #pragma unroll
        for (int q = 0; q < 4; q++) {
            float hv = fmaxf((acc2[ct][q] + bb2 - mean) * sc + bo, 0.f);
            ts[w][kg * 4 + q][col] = (ushort)f2bf(hv);
        }
    }
    // coalesced copy LDS -> h_out (full-wave uint2 stores)
    #pragma unroll
    for (int it = 0; it < 4; it++) {
        int flat = it * 64 + l;          // unit = 4 shorts
        int node = flat >> 4;
        int ch4 = (flat & 15) * 4;
        uint2 val = *(uint2*)(&ts[w][node][ch4]);
        *(uint2*)(h_out + (size_t)(nb + node) * H + ch4) = val;
    }
}

// ---------------- fused pooling + vn MLP + h += vn (addvn fused) ----------
__global__ __launch_bounds__(256) void k_poolvn(ushort* __restrict__ h,
                                                const int* __restrict__ gstart,
                                                float* __restrict__ pooled,
                                                const float* __restrict__ w1, const float* __restrict__ b1,
                                                const float* __restrict__ w2, const float* __restrict__ b2,
                                                float* __restrict__ vn, int do_vn) {
    __shared__ float ps[4][H];
    __shared__ float ts[4][H];
    int w = threadIdx.x >> 6, c = threadIdx.x & 63;
    int g = blockIdx.x * 4 + w;
    int s = __builtin_amdgcn_readfirstlane(gstart[g]);
    int e = __builtin_amdgcn_readfirstlane(gstart[g + 1]);
    float acc = 0.f;
    int n = s;
    for (; n + 4 <= e; n += 4) {
        float x0 = bf2f(h[(size_t)(n + 0) * H + c]);
        float x1 = bf2f(h[(size_t)(n + 1) * H + c]);
        float x2 = bf2f(h[(size_t)(n + 2) * H + c]);
        float x3 = bf2f(h[(size_t)(n + 3) * H + c]);
        acc += x0; acc += x1; acc += x2; acc += x3;
    }
    for (; n < e; n++) acc += bf2f(h[(size_t)n * H + c]);
    pooled[(size_t)g * H + c] = acc;
    if (!do_vn) return;
    ps[w][c] = acc;
    float a1 = b1[c];
    for (int k = 0; k < H; k += 4) {
        float4 pv = *(const float4*)&ps[w][k];
        a1 = fmaf(pv.x, w1[(k + 0) * H + c], a1);
        a1 = fmaf(pv.y, w1[(k + 1) * H + c], a1);
        a1 = fmaf(pv.z, w1[(k + 2) * H + c], a1);
        a1 = fmaf(pv.w, w1[(k + 3) * H + c], a1);
    }
    ts[w][c] = fmaxf(a1, 0.f);
    float a2 = b2[c];
    for (int k = 0; k < H; k += 4) {
        float4 tv = *(const float4*)&ts[w][k];
        a2 = fmaf(tv.x, w2[(k + 0) * H + c], a2);
        a2 = fmaf(tv.y, w2[(k + 1) * H + c], a2);
        a2 = fmaf(tv.z, w2[(k + 2) * H + c], a2);
        a2 = fmaf(tv.w, w2[(k + 3) * H + c], a2);
    }
    float vnew = vn[(size_t)g * H + c] + a2;
    vn[(size_t)g * H + c] = vnew;
    ps[w][c] = vnew;
    float vlo = ps[w][(c & 31) * 2 + 0];
    float vhi = ps[w][(c & 31) * 2 + 1];
    int ch2 = (c & 31) * 2;
    for (n = s; n + 2 <= e; n += 2) {
        size_t off = (size_t)(n + (c >> 5)) * H + ch2;
        uint u = *(uint*)(h + off);
        float lo = bf2f(u) + vlo;
        float hi = bf2f(u >> 16) + vhi;
        *(uint*)(h + off) = f2bf(lo) | (f2bf(hi) << 16);
    }
    if (n < e && c < 32) {
        size_t off = (size_t)n * H + ch2;
        uint u = *(uint*)(h + off);
        float lo = bf2f(u) + vlo;
        float hi = bf2f(u >> 16) + vhi;
        *(uint*)(h + off) = f2bf(lo) | (f2bf(hi) << 16);
    }
}

// ---------------- final: mean pool, pep MLP, classifier ----------------
__global__ __launch_bounds__(256) void k_final(const float* __restrict__ pooled,
                                               const int* __restrict__ gstart,
                                               const float* __restrict__ pep,
                                               const float* __restrict__ pw, const float* __restrict__ pb,
                                               const float* __restrict__ cw1, const float* __restrict__ cb1,
                                               const float* __restrict__ cw2, const float* __restrict__ cb2,
                                               float* __restrict__ out) {
    __shared__ float red[4][H];
    __shared__ float fused[2 * H];
    int g = blockIdx.x;
    int lane = threadIdx.x & 63;
    int part = threadIdx.x >> 6;
    const float* pr = pep + (size_t)g * PEP_DIM;
    float acc = 0.0f;
    int k0 = part * (PEP_DIM / 4);
    for (int k = k0; k < k0 + PEP_DIM / 4; k++) {
        acc += pr[k] * pw[k * H + lane];
    }
    red[part][lane] = acc;
    __syncthreads();
    if (part == 0) {
        float s = red[0][lane] + red[1][lane] + red[2][lane] + red[3][lane] + pb[lane];
        fused[H + lane] = fmaxf(s, 0.0f);
        float c = (float)(gstart[g + 1] - gstart[g]);
        float invc = 1.0f / fmaxf(c, 1.0f);
        fused[lane] = pooled[(size_t)g * H + lane] * invc;
    }
    __syncthreads();
    if (part == 0) {
        float a = cb1[lane];
        for (int k = 0; k < 2 * H; k++) a += fused[k] * cw1[k * H + lane];
        float t = fmaxf(a, 0.0f);
        float v = t * cw2[lane];
        for (int off = 32; off > 0; off >>= 1) v += __shfl_down(v, off, 64);
        if (lane == 0) out[g] = v + cb2[0];
    }
}

extern "C" void kernel_launch(void* const* d_in, const int* in_sizes, int n_in,
                              void* d_out, int out_size, void* d_ws, size_t ws_size,
                              hipStream_t stream) {
    const float* x        = (const float*)d_in[0];
    const int*   ei       = (const int*)d_in[1];
    const int*   batch    = (const int*)d_in[2];
    const float* ea       = (const float*)d_in[3];
    const float* pep      = (const float*)d_in[4];
    const float* in_w     = (const float*)d_in[5];
    const float* in_b     = (const float*)d_in[6];
    const float* e_w      = (const float*)d_in[7];
    const float* e_b      = (const float*)d_in[8];
    const float* conv_w1  = (const float*)d_in[9];
    const float* conv_b1  = (const float*)d_in[10];
    const float* conv_w2  = (const float*)d_in[11];
    const float* conv_b2  = (const float*)d_in[12];
    const float* bn_w     = (const float*)d_in[13];
    const float* bn_b     = (const float*)d_in[14];
    const float* bn_mean  = (const float*)d_in[15];
    const float* bn_var   = (const float*)d_in[16];
    const float* vn_w1    = (const float*)d_in[17];
    const float* vn_b1    = (const float*)d_in[18];
    const float* vn_w2    = (const float*)d_in[19];
    const float* vn_b2    = (const float*)d_in[20];
    const float* pep_w    = (const float*)d_in[21];
    const float* pep_b    = (const float*)d_in[22];
    const float* cls_w1   = (const float*)d_in[23];
    const float* cls_b1   = (const float*)d_in[24];
    const float* cls_w2   = (const float*)d_in[25];
    const float* cls_b2   = (const float*)d_in[26];
    float* out = (float*)d_out;

    // ---- workspace layout (16B alignment maintained) ----
    ushort* h_a   = (ushort*)d_ws;                    // NN*H bf16
    ushort* h_b   = h_a + (size_t)NN * H;             // NN*H bf16
    ushort* z     = h_b + (size_t)NN * H;             // NN*H bf16
    float* pooled = (float*)(z + (size_t)NN * H);     // NG*H
    float* vn     = pooled + (size_t)NG * H;          // NG*H
    int2*  csr    = (int2*)(vn + (size_t)NG * H);     // NE (8B each)
    ushort* wp    = (ushort*)(csr + (size_t)NE);      // 3*8192 bf16 packed weights
    int* row_start = (int*)(wp + 3 * 8192);           // NN+16
    int* cursor    = row_start + NN + 16;             // NN+16
    int* gstart    = cursor + NN + 16;                // NG+16
    int* bsum      = gstart + NG + 16;                // NB (<=128)

    // ---- build CSR (once; reused by all 3 layers) ----
    hipMemsetAsync(cursor, 0, (size_t)NN * sizeof(int), stream);
    k_degree<<<(NE + 255) / 256, 256, 0, stream>>>(ei, cursor);
    k_scan1<<<NB, 256, 0, stream>>>(cursor, bsum);
    k_scan2<<<1, 64, 0, stream>>>(bsum, row_start);
    k_scan3<<<NB, 256, 0, stream>>>(cursor, bsum, row_start, cursor);
    k_fill<<<(NE + 255) / 256, 256, 0, stream>>>(ei, ea, cursor, csr);
    k_gstart<<<(NN + 255) / 256, 256, 0, stream>>>(batch, gstart);
    k_prep<<<(3 * 8192 + 255) / 256, 256, 0, stream>>>(conv_w1, conv_w2, wp);

    // ---- init ----
    k_init_h<<<NN * 16 / 256, 256, 0, stream>>>(x, in_w, in_b, h_a);
    hipMemsetAsync(vn, 0, (size_t)NG * H * sizeof(float), stream);

    ushort* hc = h_a;
    ushort* hn = h_b;
    for (int i = 0; i < 3; i++) {
        k_gather<<<NN / CONV_W, 1024, 0, stream>>>(hc, z, csr, row_start, e_w, e_b);
        k_mlp<<<(NN + 63) / 64, 256, 0, stream>>>(z, hn, wp + i * 8192,
                                                  conv_b1 + i * H, conv_b2 + i * H,
                                                  bn_w + i * H, bn_b + i * H,
                                                  bn_mean + i * H, bn_var + i * H);
        ushort* t = hc; hc = hn; hn = t;   // hc now holds layer output
        k_poolvn<<<NG / 4, 256, 0, stream>>>(hc, gstart, pooled,
                                             vn_w1, vn_b1, vn_w2, vn_b2, vn,
                                             (i < 2) ? 1 : 0);
    }

    k_final<<<NG, 256, 0, stream>>>(pooled, gstart, pep, pep_w, pep_b,
                                    cls_w1, cls_b1, cls_w2, cls_b2, out);
}

// Round 13
// 349.638 us; speedup vs baseline: 2.2480x; 1.3518x over previous
//
#include <hip/hip_runtime.h>

#define NN 100000
#define NE 1600000
#define NG 2048
#define IN_DIM 32
#define PEP_DIM 768
#define H 64
#define BN_EPS 1e-5f
#define CONV_W 16            // waves (=nodes) per k_gather block
#define BUCK_SHIFT 9         // 512 nodes per bucket
#define NBUCK ((NN + 511) >> 9)          // 196
#define NBLKA 256                         // blocks in hist/scatter pass
#define CHUNK ((NE + NBLKA - 1) / NBLKA)  // 6250 edges per block

typedef unsigned int uint;
typedef unsigned short ushort;
typedef __attribute__((ext_vector_type(8))) __bf16 bf16x8;
typedef __attribute__((ext_vector_type(4))) float f32x4;

__device__ __forceinline__ float bf2f(uint u) {
    return __uint_as_float((u & 0xFFFFu) << 16);
}
__device__ __forceinline__ uint f2bf(float x) {
    uint b = __float_as_uint(x);
    return (b + 0x7FFFu + ((b >> 16) & 1u)) >> 16;   // RNE
}

// ======== CSR build: locality-aware bucket sort (replaces degree+scan+fill;
// old k_fill's random-time scatter cost 100MB HBM writes on a 12.8MB array) ====

// ---- pass A: per-block histogram over dst buckets ----
__global__ __launch_bounds__(256) void k_hist(const int* __restrict__ ei, int* __restrict__ mat) {
    __shared__ int hloc[NBUCK];
    for (int i = threadIdx.x; i < NBUCK; i += 256) hloc[i] = 0;
    __syncthreads();
    int base = blockIdx.x * CHUNK;
    int end = min(NE, base + CHUNK);
    for (int e = base + threadIdx.x; e < end; e += 256)
        atomicAdd(&hloc[ei[NE + e] >> BUCK_SHIFT], 1);
    __syncthreads();
    for (int i = threadIdx.x; i < NBUCK; i += 256)
        mat[i * NBLKA + blockIdx.x] = hloc[i];
}

// ---- pass B1: per-bucket exclusive scan over blocks; emit bucket totals ----
__global__ __launch_bounds__(NBLKA) void k_s1(int* __restrict__ mat, int* __restrict__ tot) {
    __shared__ int s[NBLKA];
    int b = blockIdx.x;
    int v = mat[b * NBLKA + threadIdx.x];
    s[threadIdx.x] = v;
    __syncthreads();
    for (int off = 1; off < NBLKA; off <<= 1) {
        int x = (threadIdx.x >= off) ? s[threadIdx.x - off] : 0;
        __syncthreads();
        s[threadIdx.x] += x;
        __syncthreads();
    }
    mat[b * NBLKA + threadIdx.x] = s[threadIdx.x] - v;   // exclusive
    if (threadIdx.x == NBLKA - 1) tot[b] = s[threadIdx.x];
}

// ---- pass B2: exclusive scan of bucket totals -> bucket bases ----
__global__ __launch_bounds__(256) void k_s2(const int* __restrict__ tot, int* __restrict__ bases) {
    __shared__ int s[256];
    int v = (threadIdx.x < NBUCK) ? tot[threadIdx.x] : 0;
    s[threadIdx.x] = v;
    __syncthreads();
    for (int off = 1; off < 256; off <<= 1) {
        int x = (threadIdx.x >= off) ? s[threadIdx.x - off] : 0;
        __syncthreads();
        s[threadIdx.x] += x;
        __syncthreads();
    }
    if (threadIdx.x < NBUCK) bases[threadIdx.x] = s[threadIdx.x] - v;
    if (threadIdx.x == 255) bases[NBUCK] = s[255];
}

// ---- pass C: scatter edges to bucket-contiguous tmp (LDS cursors; each
// (block,bucket) range written contiguously -> streaming lines) ----
__global__ __launch_bounds__(256) void k_scat1(const int* __restrict__ ei, const float* __restrict__ ea,
                                               const int* __restrict__ mat, const int* __restrict__ bases,
                                               int2* __restrict__ tmp) {
    __shared__ int cur[NBUCK];
    for (int i = threadIdx.x; i < NBUCK; i += 256)
        cur[i] = bases[i] + mat[i * NBLKA + blockIdx.x];
    __syncthreads();
    int base = blockIdx.x * CHUNK;
    int end = min(NE, base + CHUNK);
    for (int e = base + threadIdx.x; e < end; e += 256) {
        int dst = ei[NE + e];
        int bk = dst >> BUCK_SHIFT;
        int pos = atomicAdd(&cur[bk], 1);
        float2 a = *(const float2*)(ea + (size_t)e * 2);
        int2 r;
        r.x = ei[e] | ((dst & 511) << 17);   // src (17b) | dst_local (9b)
        r.y = (int)(f2bf(a.x) | (f2bf(a.y) << 16));
        tmp[pos] = r;
    }
}

// ---- pass D: per-bucket exact CSR placement + row_start (replaces degree/scans).
// All csr writes land in one ~64KB L2-hot region per block. ----
__global__ __launch_bounds__(256) void k_scat2(const int2* __restrict__ tmp, const int* __restrict__ bases,
                                               int2* __restrict__ csr, int* __restrict__ row_start) {
    __shared__ int deg[512];
    __shared__ int psc[256];
    __shared__ int cur[512];
    int b = blockIdx.x;
    int t = threadIdx.x;
    int s0 = bases[b], s1 = bases[b + 1];
    deg[2 * t] = 0; deg[2 * t + 1] = 0;
    __syncthreads();
    for (int e = s0 + t; e < s1; e += 256)
        atomicAdd(&deg[(tmp[e].x >> 17) & 511], 1);
    __syncthreads();
    int d0 = deg[2 * t], d1 = deg[2 * t + 1];
    psc[t] = d0 + d1;
    __syncthreads();
    for (int off = 1; off < 256; off <<= 1) {
        int x = (t >= off) ? psc[t - off] : 0;
        __syncthreads();
        psc[t] += x;
        __syncthreads();
    }
    int ep = psc[t] - (d0 + d1);          // exclusive over pairs
    int node0 = (b << BUCK_SHIFT) + 2 * t;
    int e0 = s0 + ep, e1 = e0 + d0;
    cur[2 * t] = e0; cur[2 * t + 1] = e1;
    if (node0 < NN) row_start[node0] = e0;
    if (node0 + 1 < NN) row_start[node0 + 1] = e1;
    __syncthreads();
    for (int e = s0 + t; e < s1; e += 256) {
        int2 r = tmp[e];
        int nl = (r.x >> 17) & 511;
        int pos = atomicAdd(&cur[nl], 1);
        int2 o;
        o.x = r.x & 0x1FFFF;
        o.y = r.y;
        csr[pos] = o;
    }
    if (b == NBUCK - 1 && t == 0) row_start[NN] = NE;
}

// ---------------- graph boundaries from sorted batch ----------------
__global__ void k_gstart(const int* __restrict__ batch, int* __restrict__ gstart) {
    int i = blockIdx.x * 256 + threadIdx.x;
    if (i >= NN) return;
    int b = batch[i];
    int p = (i == 0) ? -1 : batch[i - 1];
    for (int g = p + 1; g <= b; g++) gstart[g] = i;
    if (i == NN - 1) {
        for (int g = b + 1; g <= NG; g++) gstart[g] = NN;
    }
}

// ---------------- h0 = x @ in_w + in_b (bf16 out) ----------------
__global__ void k_init_h(const float* __restrict__ x, const float* __restrict__ w,
                         const float* __restrict__ b, ushort* __restrict__ h) {
    int t = blockIdx.x * 256 + threadIdx.x;
    int node = t >> 4;
    if (node >= NN) return;
    int c4 = (t & 15) * 4;
    float4 acc = *(const float4*)(b + c4);
    const float* xr = x + node * IN_DIM;
    for (int k = 0; k < IN_DIM; k++) {
        float xv = xr[k];
        float4 wv = *(const float4*)(w + k * H + c4);
        acc.x += xv * wv.x; acc.y += xv * wv.y;
        acc.z += xv * wv.z; acc.w += xv * wv.w;
    }
    uint2 o;
    o.x = f2bf(acc.x) | (f2bf(acc.y) << 16);
    o.y = f2bf(acc.z) | (f2bf(acc.w) << 16);
    *(uint2*)(h + (size_t)node * H + c4) = o;
}

// ---------------- pack conv weights into MFMA B-fragment layout ----------
__global__ void k_prep(const float* __restrict__ w1, const float* __restrict__ w2,
                       ushort* __restrict__ wp) {
    int t = blockIdx.x * 256 + threadIdx.x;
    if (t >= 3 * 8192) return;
    int j = t & 7;
    int lane = (t >> 3) & 63;
    int ct = (t >> 9) & 3;
    int ks = (t >> 11) & 1;
    int st = (t >> 12) & 1;
    int ly = t >> 13;
    int k = ks * 32 + (lane >> 4) * 8 + j;
    int c = ct * 16 + (lane & 15);
    const float* src = (st == 0) ? w1 : w2;
    wp[t] = (ushort)f2bf(src[ly * H * H + k * H + c]);
}

// ---------------- gather only: z = h_self + sum relu(h[src]+e) ----------
__global__ __launch_bounds__(1024, 4) void k_gather(
    const ushort* __restrict__ h_in, ushort* __restrict__ z,
    const int2* __restrict__ csr, const int* __restrict__ row_start,
    const float* __restrict__ ew, const float* __restrict__ eb) {
    int w = threadIdx.x >> 6;
    int c = threadIdx.x & 63;
    int node = blockIdx.x * CONV_W + w;
    float ew0 = ew[c], ew1 = ew[H + c], ebc = eb[c];
    int rs = __builtin_amdgcn_readfirstlane(row_start[node]);
    int re = __builtin_amdgcn_readfirstlane(row_start[node + 1]);
    float acc = 0.f;
    int j = rs;
    for (; j + 16 <= re; j += 16) {
        int2 v[16];
        #pragma unroll
        for (int t = 0; t < 16; t++) v[t] = csr[j + t];
        float hh[16];
        #pragma unroll
        for (int t = 0; t < 16; t++) hh[t] = bf2f(h_in[(size_t)v[t].x * H + c]);
        #pragma unroll
        for (int t = 0; t < 16; t++)
            acc += fmaxf(hh[t] + fmaf(bf2f(v[t].y), ew0, fmaf(bf2f((uint)v[t].y >> 16), ew1, ebc)), 0.f);
    }
    for (; j + 4 <= re; j += 4) {
        int2 v[4];
        #pragma unroll
        for (int t = 0; t < 4; t++) v[t] = csr[j + t];
        float hh[4];
        #pragma unroll
        for (int t = 0; t < 4; t++) hh[t] = bf2f(h_in[(size_t)v[t].x * H + c]);
        #pragma unroll
        for (int t = 0; t < 4; t++)
            acc += fmaxf(hh[t] + fmaf(bf2f(v[t].y), ew0, fmaf(bf2f((uint)v[t].y >> 16), ew1, ebc)), 0.f);
    }
    for (; j < re; j++) {
        int2 v = csr[j];
        float hs = bf2f(h_in[(size_t)v.x * H + c]);
        acc += fmaxf(hs + fmaf(bf2f(v.y), ew0, fmaf(bf2f((uint)v.y >> 16), ew1, ebc)), 0.f);
    }
    float zv = bf2f(h_in[(size_t)node * H + c]) + acc;
    uint me = f2bf(zv);
    uint nb2 = __shfl_down(me, 1, 64);
    if ((c & 1) == 0) {
        *(uint*)(z + (size_t)node * H + c) = me | (nb2 << 16);
    }
}

// ---------------- MFMA MLP: h_out = relu(BN(relu(z@W1+b1)@W2+b2)) --------
__global__ __launch_bounds__(256, 4) void k_mlp(
    const ushort* __restrict__ z, ushort* __restrict__ h_out,
    const ushort* __restrict__ wp,
    const float* __restrict__ b1, const float* __restrict__ b2,
    const float* __restrict__ bnw, const float* __restrict__ bnb,
    const float* __restrict__ bnm, const float* __restrict__ bnv) {
    __shared__ ushort ts[4][16][72];
    int w = threadIdx.x >> 6;
    int l = threadIdx.x & 63;
    int nb = blockIdx.x * 64 + w * 16;
    if (nb >= NN) return;
    int r = l & 15;
    int kg = l >> 4;
    const ushort* zr = z + (size_t)(nb + r) * H + kg * 8;
    bf16x8 A0 = *(const bf16x8*)(zr);
    bf16x8 A1 = *(const bf16x8*)(zr + 32);
    f32x4 acc[4];
    #pragma unroll
    for (int ct = 0; ct < 4; ct++) {
        bf16x8 B0 = *(const bf16x8*)(wp + (0 * 4 + ct) * 512 + l * 8);
        bf16x8 B1 = *(const bf16x8*)(wp + (1 * 4 + ct) * 512 + l * 8);
        f32x4 a = {0.f, 0.f, 0.f, 0.f};
        a = __builtin_amdgcn_mfma_f32_16x16x32_bf16(A0, B0, a, 0, 0, 0);
        a = __builtin_amdgcn_mfma_f32_16x16x32_bf16(A1, B1, a, 0, 0, 0);
        acc[ct] = a;
    }
    #pragma unroll
    for (int ct = 0; ct < 4; ct++) {
        int col = ct * 16 + r;
        float bb = b1[col];
        #pragma unroll
        for (int q = 0; q < 4; q++) {
            float tv = fmaxf(acc[ct][q] + bb, 0.f);
            ts[w][kg * 4 + q][col] = (ushort)f2bf(tv);
        }
    }
    bf16x8 T0 = *(const bf16x8*)(&ts[w][r][kg * 8]);
    bf16x8 T1 = *(const bf16x8*)(&ts[w][r][32 + kg * 8]);
    f32x4 acc2[4];
    #pragma unroll
    for (int ct = 0; ct < 4; ct++) {
        bf16x8 B0 = *(const bf16x8*)(wp + 4096 + (0 * 4 + ct) * 512 + l * 8);
        bf16x8 B1 = *(const bf16x8*)(wp + 4096 + (1 * 4 + ct) * 512 + l * 8);
        f32x4 a = {0.f, 0.f, 0.f, 0.f};
        a = __builtin_amdgcn_mfma_f32_16x16x32_bf16(T0, B0, a, 0, 0, 0);
        a = __builtin_amdgcn_mfma_f32_16x16x32_bf16(T1, B1, a, 0, 0, 0);
        acc2[ct] = a;
    }
    #pragma unroll
    for (int ct = 0; ct < 4; ct++) {
        int col = ct * 16 + r;
        float bb2 = b2[col];
        float mean = bnm[col];
        float sc = bnw[col] * rsqrtf(bnv[col] + BN_EPS);
        float bo = bnb[col];
        #pragma unroll
        for (int q = 0; q < 4; q++) {
            float hv = fmaxf((acc2[ct][q] + bb2 - mean) * sc + bo, 0.f);
            ts[w][kg * 4 + q][col] = (ushort)f2bf(hv);
        }
    }
    #pragma unroll
    for (int it = 0; it < 4; it++) {
        int flat = it * 64 + l;
        int node = flat >> 4;
        int ch4 = (flat & 15) * 4;
        uint2 val = *(uint2*)(&ts[w][node][ch4]);
        *(uint2*)(h_out + (size_t)(nb + node) * H + ch4) = val;
    }
}

// ---------------- fused pooling + vn MLP + h += vn ----------
__global__ __launch_bounds__(256) void k_poolvn(ushort* __restrict__ h,
                                                const int* __restrict__ gstart,
                                                float* __restrict__ pooled,
                                                const float* __restrict__ w1, const float* __restrict__ b1,
                                                const float* __restrict__ w2, const float* __restrict__ b2,
                                                float* __restrict__ vn, int do_vn) {
    __shared__ float ps[4][H];
    __shared__ float ts[4][H];
    int w = threadIdx.x >> 6, c = threadIdx.x & 63;
    int g = blockIdx.x * 4 + w;
    int s = __builtin_amdgcn_readfirstlane(gstart[g]);
    int e = __builtin_amdgcn_readfirstlane(gstart[g + 1]);
    float acc = 0.f;
    int n = s;
    for (; n + 4 <= e; n += 4) {
        float x0 = bf2f(h[(size_t)(n + 0) * H + c]);
        float x1 = bf2f(h[(size_t)(n + 1) * H + c]);
        float x2 = bf2f(h[(size_t)(n + 2) * H + c]);
        float x3 = bf2f(h[(size_t)(n + 3) * H + c]);
        acc += x0; acc += x1; acc += x2; acc += x3;
    }
    for (; n < e; n++) acc += bf2f(h[(size_t)n * H + c]);
    pooled[(size_t)g * H + c] = acc;
    if (!do_vn) return;
    ps[w][c] = acc;
    float a1 = b1[c];
    for (int k = 0; k < H; k += 4) {
        float4 pv = *(const float4*)&ps[w][k];
        a1 = fmaf(pv.x, w1[(k + 0) * H + c], a1);
        a1 = fmaf(pv.y, w1[(k + 1) * H + c], a1);
        a1 = fmaf(pv.z, w1[(k + 2) * H + c], a1);
        a1 = fmaf(pv.w, w1[(k + 3) * H + c], a1);
    }
    ts[w][c] = fmaxf(a1, 0.f);
    float a2 = b2[c];
    for (int k = 0; k < H; k += 4) {
        float4 tv = *(const float4*)&ts[w][k];
        a2 = fmaf(tv.x, w2[(k + 0) * H + c], a2);
        a2 = fmaf(tv.y, w2[(k + 1) * H + c], a2);
        a2 = fmaf(tv.z, w2[(k + 2) * H + c], a2);
        a2 = fmaf(tv.w, w2[(k + 3) * H + c], a2);
    }
    float vnew = vn[(size_t)g * H + c] + a2;
    vn[(size_t)g * H + c] = vnew;
    ps[w][c] = vnew;
    float vlo = ps[w][(c & 31) * 2 + 0];
    float vhi = ps[w][(c & 31) * 2 + 1];
    int ch2 = (c & 31) * 2;
    for (n = s; n + 2 <= e; n += 2) {
        size_t off = (size_t)(n + (c >> 5)) * H + ch2;
        uint u = *(uint*)(h + off);
        float lo = bf2f(u) + vlo;
        float hi = bf2f(u >> 16) + vhi;
        *(uint*)(h + off) = f2bf(lo) | (f2bf(hi) << 16);
    }
    if (n < e && c < 32) {
        size_t off = (size_t)n * H + ch2;
        uint u = *(uint*)(h + off);
        float lo = bf2f(u) + vlo;
        float hi = bf2f(u >> 16) + vhi;
        *(uint*)(h + off) = f2bf(lo) | (f2bf(hi) << 16);
    }
}

// ---------------- final: mean pool, pep MLP, classifier ----------------
__global__ __launch_bounds__(256) void k_final(const float* __restrict__ pooled,
                                               const int* __restrict__ gstart,
                                               const float* __restrict__ pep,
                                               const float* __restrict__ pw, const float* __restrict__ pb,
                                               const float* __restrict__ cw1, const float* __restrict__ cb1,
                                               const float* __restrict__ cw2, const float* __restrict__ cb2,
                                               float* __restrict__ out) {
    __shared__ float red[4][H];
    __shared__ float fused[2 * H];
    int g = blockIdx.x;
    int lane = threadIdx.x & 63;
    int part = threadIdx.x >> 6;
    const float* pr = pep + (size_t)g * PEP_DIM;
    float acc = 0.0f;
    int k0 = part * (PEP_DIM / 4);
    for (int k = k0; k < k0 + PEP_DIM / 4; k++) {
        acc += pr[k] * pw[k * H + lane];
    }
    red[part][lane] = acc;
    __syncthreads();
    if (part == 0) {
        float s = red[0][lane] + red[1][lane] + red[2][lane] + red[3][lane] + pb[lane];
        fused[H + lane] = fmaxf(s, 0.0f);
        float c = (float)(gstart[g + 1] - gstart[g]);
        float invc = 1.0f / fmaxf(c, 1.0f);
        fused[lane] = pooled[(size_t)g * H + lane] * invc;
    }
    __syncthreads();
    if (part == 0) {
        float a = cb1[lane];
        for (int k = 0; k < 2 * H; k++) a += fused[k] * cw1[k * H + lane];
        float t = fmaxf(a, 0.0f);
        float v = t * cw2[lane];
        for (int off = 32; off > 0; off >>= 1) v += __shfl_down(v, off, 64);
        if (lane == 0) out[g] = v + cb2[0];
    }
}

extern "C" void kernel_launch(void* const* d_in, const int* in_sizes, int n_in,
                              void* d_out, int out_size, void* d_ws, size_t ws_size,
                              hipStream_t stream) {
    const float* x        = (const float*)d_in[0];
    const int*   ei       = (const int*)d_in[1];
    const int*   batch    = (const int*)d_in[2];
    const float* ea       = (const float*)d_in[3];
    const float* pep      = (const float*)d_in[4];
    const float* in_w     = (const float*)d_in[5];
    const float* in_b     = (const float*)d_in[6];
    const float* e_w      = (const float*)d_in[7];
    const float* e_b      = (const float*)d_in[8];
    const float* conv_w1  = (const float*)d_in[9];
    const float* conv_b1  = (const float*)d_in[10];
    const float* conv_w2  = (const float*)d_in[11];
    const float* conv_b2  = (const float*)d_in[12];
    const float* bn_w     = (const float*)d_in[13];
    const float* bn_b     = (const float*)d_in[14];
    const float* bn_mean  = (const float*)d_in[15];
    const float* bn_var   = (const float*)d_in[16];
    const float* vn_w1    = (const float*)d_in[17];
    const float* vn_b1    = (const float*)d_in[18];
    const float* vn_w2    = (const float*)d_in[19];
    const float* vn_b2    = (const float*)d_in[20];
    const float* pep_w    = (const float*)d_in[21];
    const float* pep_b    = (const float*)d_in[22];
    const float* cls_w1   = (const float*)d_in[23];
    const float* cls_b1   = (const float*)d_in[24];
    const float* cls_w2   = (const float*)d_in[25];
    const float* cls_b2   = (const float*)d_in[26];
    float* out = (float*)d_out;

    // ---- workspace layout (16B alignment maintained) ----
    ushort* h_a   = (ushort*)d_ws;                    // NN*H bf16
    ushort* h_b   = h_a + (size_t)NN * H;             // NN*H bf16
    ushort* z     = h_b + (size_t)NN * H;             // NN*H bf16 (aliased as tmp during CSR build)
    int2*  tmp    = (int2*)z;                         // NE int2 == NN*H*2B, disjoint lifetime
    float* pooled = (float*)(z + (size_t)NN * H);     // NG*H
    float* vn     = pooled + (size_t)NG * H;          // NG*H
    int2*  csr    = (int2*)(vn + (size_t)NG * H);     // NE (8B each)
    ushort* wp    = (ushort*)(csr + (size_t)NE);      // 3*8192 bf16 packed weights
    int* row_start = (int*)(wp + 3 * 8192);           // NN+16
    int* gstart    = row_start + NN + 16;             // NG+16
    int* mat       = gstart + NG + 16;                // NBUCK*NBLKA
    int* tot       = mat + NBUCK * NBLKA;             // NBUCK
    int* bases     = tot + NBUCK;                     // NBUCK+1

    // ---- build CSR via bucket sort (once; reused by all 3 layers) ----
    k_hist<<<NBLKA, 256, 0, stream>>>(ei, mat);
    k_s1<<<NBUCK, NBLKA, 0, stream>>>(mat, tot);
    k_s2<<<1, 256, 0, stream>>>(tot, bases);
    k_scat1<<<NBLKA, 256, 0, stream>>>(ei, ea, mat, bases, tmp);
    k_scat2<<<NBUCK, 256, 0, stream>>>(tmp, bases, csr, row_start);
    k_gstart<<<(NN + 255) / 256, 256, 0, stream>>>(batch, gstart);
    k_prep<<<(3 * 8192 + 255) / 256, 256, 0, stream>>>(conv_w1, conv_w2, wp);

    // ---- init ----
    k_init_h<<<NN * 16 / 256, 256, 0, stream>>>(x, in_w, in_b, h_a);
    hipMemsetAsync(vn, 0, (size_t)NG * H * sizeof(float), stream);

    ushort* hc = h_a;
    ushort* hn = h_b;
    for (int i = 0; i < 3; i++) {
        k_gather<<<NN / CONV_W, 1024, 0, stream>>>(hc, z, csr, row_start, e_w, e_b);
        k_mlp<<<(NN + 63) / 64, 256, 0, stream>>>(z, hn, wp + i * 8192,
                                                  conv_b1 + i * H, conv_b2 + i * H,
                                                  bn_w + i * H, bn_b + i * H,
                                                  bn_mean + i * H, bn_var + i * H);
        ushort* t = hc; hc = hn; hn = t;   // hc now holds layer output
        k_poolvn<<<NG / 4, 256, 0, stream>>>(hc, gstart, pooled,
                                             vn_w1, vn_b1, vn_w2, vn_b2, vn,
                                             (i < 2) ? 1 : 0);
    }

    k_final<<<NG, 256, 0, stream>>>(pooled, gstart, pep, pep_w, pep_b,
                                    cls_w1, cls_b1, cls_w2, cls_b2, out);
}

// Round 14
// 312.866 us; speedup vs baseline: 2.5122x; 1.1175x over previous
//
#include <hip/hip_runtime.h>

#define NN 100000
#define NE 1600000
#define NG 2048
#define IN_DIM 32
#define PEP_DIM 768
#define H 64
#define BN_EPS 1e-5f
#define CONV_W 16            // waves (=nodes) per k_gather block
#define NGRP (NN / CONV_W)   // 6250 node groups
#define GATHER_BLOCKS 512    // persistent: 2 blocks/CU x 256 CUs
#define BUCK_SHIFT 9         // 512 nodes per bucket
#define NBUCK ((NN + 511) >> 9)          // 196
#define NBLKA 256                         // blocks in hist/scatter pass
#define CHUNK ((NE + NBLKA - 1) / NBLKA)  // 6250 edges per block

typedef unsigned int uint;
typedef unsigned short ushort;
typedef __attribute__((ext_vector_type(8))) __bf16 bf16x8;
typedef __attribute__((ext_vector_type(4))) float f32x4;

__device__ __forceinline__ float bf2f(uint u) {
    return __uint_as_float((u & 0xFFFFu) << 16);
}
__device__ __forceinline__ uint f2bf(float x) {
    uint b = __float_as_uint(x);
    return (b + 0x7FFFu + ((b >> 16) & 1u)) >> 16;   // RNE
}

// ======== CSR build: locality-aware bucket sort ========

// ---- pass A: per-block histogram over dst buckets ----
__global__ __launch_bounds__(256) void k_hist(const int* __restrict__ ei, int* __restrict__ mat) {
    __shared__ int hloc[NBUCK];
    for (int i = threadIdx.x; i < NBUCK; i += 256) hloc[i] = 0;
    __syncthreads();
    int base = blockIdx.x * CHUNK;
    int end = min(NE, base + CHUNK);
    for (int e = base + threadIdx.x; e < end; e += 256)
        atomicAdd(&hloc[ei[NE + e] >> BUCK_SHIFT], 1);
    __syncthreads();
    for (int i = threadIdx.x; i < NBUCK; i += 256)
        mat[i * NBLKA + blockIdx.x] = hloc[i];
}

// ---- pass B1: per-bucket exclusive scan over blocks; emit bucket totals ----
__global__ __launch_bounds__(NBLKA) void k_s1(int* __restrict__ mat, int* __restrict__ tot) {
    __shared__ int s[NBLKA];
    int b = blockIdx.x;
    int v = mat[b * NBLKA + threadIdx.x];
    s[threadIdx.x] = v;
    __syncthreads();
    for (int off = 1; off < NBLKA; off <<= 1) {
        int x = (threadIdx.x >= off) ? s[threadIdx.x - off] : 0;
        __syncthreads();
        s[threadIdx.x] += x;
        __syncthreads();
    }
    mat[b * NBLKA + threadIdx.x] = s[threadIdx.x] - v;   // exclusive
    if (threadIdx.x == NBLKA - 1) tot[b] = s[threadIdx.x];
}

// ---- pass B2: exclusive scan of bucket totals -> bucket bases ----
__global__ __launch_bounds__(256) void k_s2(const int* __restrict__ tot, int* __restrict__ bases) {
    __shared__ int s[256];
    int v = (threadIdx.x < NBUCK) ? tot[threadIdx.x] : 0;
    s[threadIdx.x] = v;
    __syncthreads();
    for (int off = 1; off < 256; off <<= 1) {
        int x = (threadIdx.x >= off) ? s[threadIdx.x - off] : 0;
        __syncthreads();
        s[threadIdx.x] += x;
        __syncthreads();
    }
    if (threadIdx.x < NBUCK) bases[threadIdx.x] = s[threadIdx.x] - v;
    if (threadIdx.x == 255) bases[NBUCK] = s[255];
}

// ---- pass C: scatter edges to bucket-contiguous tmp ----
__global__ __launch_bounds__(256) void k_scat1(const int* __restrict__ ei, const float* __restrict__ ea,
                                               const int* __restrict__ mat, const int* __restrict__ bases,
                                               int2* __restrict__ tmp) {
    __shared__ int cur[NBUCK];
    for (int i = threadIdx.x; i < NBUCK; i += 256)
        cur[i] = bases[i] + mat[i * NBLKA + blockIdx.x];
    __syncthreads();
    int base = blockIdx.x * CHUNK;
    int end = min(NE, base + CHUNK);
    for (int e = base + threadIdx.x; e < end; e += 256) {
        int dst = ei[NE + e];
        int bk = dst >> BUCK_SHIFT;
        int pos = atomicAdd(&cur[bk], 1);
        float2 a = *(const float2*)(ea + (size_t)e * 2);
        int2 r;
        r.x = ei[e] | ((dst & 511) << 17);   // src (17b) | dst_local (9b)
        r.y = (int)(f2bf(a.x) | (f2bf(a.y) << 16));
        tmp[pos] = r;
    }
}

// ---- pass D: per-bucket exact CSR placement + row_start ----
__global__ __launch_bounds__(256) void k_scat2(const int2* __restrict__ tmp, const int* __restrict__ bases,
                                               int2* __restrict__ csr, int* __restrict__ row_start) {
    __shared__ int deg[512];
    __shared__ int psc[256];
    __shared__ int cur[512];
    int b = blockIdx.x;
    int t = threadIdx.x;
    int s0 = bases[b], s1 = bases[b + 1];
    deg[2 * t] = 0; deg[2 * t + 1] = 0;
    __syncthreads();
    for (int e = s0 + t; e < s1; e += 256)
        atomicAdd(&deg[(tmp[e].x >> 17) & 511], 1);
    __syncthreads();
    int d0 = deg[2 * t], d1 = deg[2 * t + 1];
    psc[t] = d0 + d1;
    __syncthreads();
    for (int off = 1; off < 256; off <<= 1) {
        int x = (t >= off) ? psc[t - off] : 0;
        __syncthreads();
        psc[t] += x;
        __syncthreads();
    }
    int ep = psc[t] - (d0 + d1);          // exclusive over pairs
    int node0 = (b << BUCK_SHIFT) + 2 * t;
    int e0 = s0 + ep, e1 = e0 + d0;
    cur[2 * t] = e0; cur[2 * t + 1] = e1;
    if (node0 < NN) row_start[node0] = e0;
    if (node0 + 1 < NN) row_start[node0 + 1] = e1;
    __syncthreads();
    for (int e = s0 + t; e < s1; e += 256) {
        int2 r = tmp[e];
        int nl = (r.x >> 17) & 511;
        int pos = atomicAdd(&cur[nl], 1);
        int2 o;
        o.x = r.x & 0x1FFFF;
        o.y = r.y;
        csr[pos] = o;
    }
    if (b == NBUCK - 1 && t == 0) row_start[NN] = NE;
}

// ---------------- graph boundaries from sorted batch ----------------
__global__ void k_gstart(const int* __restrict__ batch, int* __restrict__ gstart) {
    int i = blockIdx.x * 256 + threadIdx.x;
    if (i >= NN) return;
    int b = batch[i];
    int p = (i == 0) ? -1 : batch[i - 1];
    for (int g = p + 1; g <= b; g++) gstart[g] = i;
    if (i == NN - 1) {
        for (int g = b + 1; g <= NG; g++) gstart[g] = NN;
    }
}

// ---------------- h0 = x @ in_w + in_b (bf16 out) ----------------
__global__ void k_init_h(const float* __restrict__ x, const float* __restrict__ w,
                         const float* __restrict__ b, ushort* __restrict__ h) {
    int t = blockIdx.x * 256 + threadIdx.x;
    int node = t >> 4;
    if (node >= NN) return;
    int c4 = (t & 15) * 4;
    float4 acc = *(const float4*)(b + c4);
    const float* xr = x + node * IN_DIM;
    for (int k = 0; k < IN_DIM; k++) {
        float xv = xr[k];
        float4 wv = *(const float4*)(w + k * H + c4);
        acc.x += xv * wv.x; acc.y += xv * wv.y;
        acc.z += xv * wv.z; acc.w += xv * wv.w;
    }
    uint2 o;
    o.x = f2bf(acc.x) | (f2bf(acc.y) << 16);
    o.y = f2bf(acc.z) | (f2bf(acc.w) << 16);
    *(uint2*)(h + (size_t)node * H + c4) = o;
}

// ---------------- pack conv weights into MFMA B-fragment layout ----------
__global__ void k_prep(const float* __restrict__ w1, const float* __restrict__ w2,
                       ushort* __restrict__ wp) {
    int t = blockIdx.x * 256 + threadIdx.x;
    if (t >= 3 * 8192) return;
    int j = t & 7;
    int lane = (t >> 3) & 63;
    int ct = (t >> 9) & 3;
    int ks = (t >> 11) & 1;
    int st = (t >> 12) & 1;
    int ly = t >> 13;
    int k = ks * 32 + (lane >> 4) * 8 + j;
    int c = ct * 16 + (lane & 15);
    const float* src = (st == 0) ? w1 : w2;
    wp[t] = (ushort)f2bf(src[ly * H * H + k * H + c]);
}

// ---------------- gather only: z = h_self + sum relu(h[src]+e) ----------
// PERSISTENT: 512 blocks (2/CU), grid-stride over node groups. r13 showed
// occupancy capped at 54% by workgroup dispatch rate (6250 tiny blocks,
// ~114 blk/us needed); persistent blocks hold 32 waves/CU from t=0.
__global__ __launch_bounds__(1024, 4) void k_gather(
    const ushort* __restrict__ h_in, ushort* __restrict__ z,
    const int2* __restrict__ csr, const int* __restrict__ row_start,
    const float* __restrict__ ew, const float* __restrict__ eb) {
    int w = threadIdx.x >> 6;
    int c = threadIdx.x & 63;
    float ew0 = ew[c], ew1 = ew[H + c], ebc = eb[c];
    for (int grp = blockIdx.x; grp < NGRP; grp += GATHER_BLOCKS) {
        int node = grp * CONV_W + w;
        int rs = __builtin_amdgcn_readfirstlane(row_start[node]);
        int re = __builtin_amdgcn_readfirstlane(row_start[node + 1]);
        float acc = 0.f;
        int j = rs;
        for (; j + 16 <= re; j += 16) {
            int2 v[16];
            #pragma unroll
            for (int t = 0; t < 16; t++) v[t] = csr[j + t];
            float hh[16];
            #pragma unroll
            for (int t = 0; t < 16; t++) hh[t] = bf2f(h_in[(size_t)v[t].x * H + c]);
            #pragma unroll
            for (int t = 0; t < 16; t++)
                acc += fmaxf(hh[t] + fmaf(bf2f(v[t].y), ew0, fmaf(bf2f((uint)v[t].y >> 16), ew1, ebc)), 0.f);
        }
        for (; j + 4 <= re; j += 4) {
            int2 v[4];
            #pragma unroll
            for (int t = 0; t < 4; t++) v[t] = csr[j + t];
            float hh[4];
            #pragma unroll
            for (int t = 0; t < 4; t++) hh[t] = bf2f(h_in[(size_t)v[t].x * H + c]);
            #pragma unroll
            for (int t = 0; t < 4; t++)
                acc += fmaxf(hh[t] + fmaf(bf2f(v[t].y), ew0, fmaf(bf2f((uint)v[t].y >> 16), ew1, ebc)), 0.f);
        }
        for (; j < re; j++) {
            int2 v = csr[j];
            float hs = bf2f(h_in[(size_t)v.x * H + c]);
            acc += fmaxf(hs + fmaf(bf2f(v.y), ew0, fmaf(bf2f((uint)v.y >> 16), ew1, ebc)), 0.f);
        }
        float zv = bf2f(h_in[(size_t)node * H + c]) + acc;
        uint me = f2bf(zv);
        uint nb2 = __shfl_down(me, 1, 64);
        if ((c & 1) == 0) {
            *(uint*)(z + (size_t)node * H + c) = me | (nb2 << 16);
        }
    }
}

// ---------------- MFMA MLP: h_out = relu(BN(relu(z@W1+b1)@W2+b2)) --------
__global__ __launch_bounds__(256, 4) void k_mlp(
    const ushort* __restrict__ z, ushort* __restrict__ h_out,
    const ushort* __restrict__ wp,
    const float* __restrict__ b1, const float* __restrict__ b2,
    const float* __restrict__ bnw, const float* __restrict__ bnb,
    const float* __restrict__ bnm, const float* __restrict__ bnv) {
    __shared__ ushort ts[4][16][72];
    int w = threadIdx.x >> 6;
    int l = threadIdx.x & 63;
    int nb = blockIdx.x * 64 + w * 16;
    if (nb >= NN) return;
    int r = l & 15;
    int kg = l >> 4;
    const ushort* zr = z + (size_t)(nb + r) * H + kg * 8;
    bf16x8 A0 = *(const bf16x8*)(zr);
    bf16x8 A1 = *(const bf16x8*)(zr + 32);
    f32x4 acc[4];
    #pragma unroll
    for (int ct = 0; ct < 4; ct++) {
        bf16x8 B0 = *(const bf16x8*)(wp + (0 * 4 + ct) * 512 + l * 8);
        bf16x8 B1 = *(const bf16x8*)(wp + (1 * 4 + ct) * 512 + l * 8);
        f32x4 a = {0.f, 0.f, 0.f, 0.f};
        a = __builtin_amdgcn_mfma_f32_16x16x32_bf16(A0, B0, a, 0, 0, 0);
        a = __builtin_amdgcn_mfma_f32_16x16x32_bf16(A1, B1, a, 0, 0, 0);
        acc[ct] = a;
    }
    #pragma unroll
    for (int ct = 0; ct < 4; ct++) {
        int col = ct * 16 + r;
        float bb = b1[col];
        #pragma unroll
        for (int q = 0; q < 4; q++) {
            float tv = fmaxf(acc[ct][q] + bb, 0.f);
            ts[w][kg * 4 + q][col] = (ushort)f2bf(tv);
        }
    }
    bf16x8 T0 = *(const bf16x8*)(&ts[w][r][kg * 8]);
    bf16x8 T1 = *(const bf16x8*)(&ts[w][r][32 + kg * 8]);
    f32x4 acc2[4];
    #pragma unroll
    for (int ct = 0; ct < 4; ct++) {
        bf16x8 B0 = *(const bf16x8*)(wp + 4096 + (0 * 4 + ct) * 512 + l * 8);
        bf16x8 B1 = *(const bf16x8*)(wp + 4096 + (1 * 4 + ct) * 512 + l * 8);
        f32x4 a = {0.f, 0.f, 0.f, 0.f};
        a = __builtin_amdgcn_mfma_f32_16x16x32_bf16(T0, B0, a, 0, 0, 0);
        a = __builtin_amdgcn_mfma_f32_16x16x32_bf16(T1, B1, a, 0, 0, 0);
        acc2[ct] = a;
    }
    #pragma unroll
    for (int ct = 0; ct < 4; ct++) {
        int col = ct * 16 + r;
        float bb2 = b2[col];
        float mean = bnm[col];
        float sc = bnw[col] * rsqrtf(bnv[col] + BN_EPS);
        float bo = bnb[col];
        #pragma unroll
        for (int q = 0; q < 4; q++) {
            float hv = fmaxf((acc2[ct][q] + bb2 - mean) * sc + bo, 0.f);
            ts[w][kg * 4 + q][col] = (ushort)f2bf(hv);
        }
    }
    #pragma unroll
    for (int it = 0; it < 4; it++) {
        int flat = it * 64 + l;
        int node = flat >> 4;
        int ch4 = (flat & 15) * 4;
        uint2 val = *(uint2*)(&ts[w][node][ch4]);
        *(uint2*)(h_out + (size_t)(nb + node) * H + ch4) = val;
    }
}

// ---------------- fused pooling + vn MLP + h += vn ----------
__global__ __launch_bounds__(256) void k_poolvn(ushort* __restrict__ h,
                                                const int* __restrict__ gstart,
                                                float* __restrict__ pooled,
                                                const float* __restrict__ w1, const float* __restrict__ b1,
                                                const float* __restrict__ w2, const float* __restrict__ b2,
                                                float* __restrict__ vn, int do_vn) {
    __shared__ float ps[4][H];
    __shared__ float ts[4][H];
    int w = threadIdx.x >> 6, c = threadIdx.x & 63;
    int g = blockIdx.x * 4 + w;
    int s = __builtin_amdgcn_readfirstlane(gstart[g]);
    int e = __builtin_amdgcn_readfirstlane(gstart[g + 1]);
    float acc = 0.f;
    int n = s;
    for (; n + 4 <= e; n += 4) {
        float x0 = bf2f(h[(size_t)(n + 0) * H + c]);
        float x1 = bf2f(h[(size_t)(n + 1) * H + c]);
        float x2 = bf2f(h[(size_t)(n + 2) * H + c]);
        float x3 = bf2f(h[(size_t)(n + 3) * H + c]);
        acc += x0; acc += x1; acc += x2; acc += x3;
    }
    for (; n < e; n++) acc += bf2f(h[(size_t)n * H + c]);
    pooled[(size_t)g * H + c] = acc;
    if (!do_vn) return;
    ps[w][c] = acc;
    float a1 = b1[c];
    for (int k = 0; k < H; k += 4) {
        float4 pv = *(const float4*)&ps[w][k];
        a1 = fmaf(pv.x, w1[(k + 0) * H + c], a1);
        a1 = fmaf(pv.y, w1[(k + 1) * H + c], a1);
        a1 = fmaf(pv.z, w1[(k + 2) * H + c], a1);
        a1 = fmaf(pv.w, w1[(k + 3) * H + c], a1);
    }
    ts[w][c] = fmaxf(a1, 0.f);
    float a2 = b2[c];
    for (int k = 0; k < H; k += 4) {
        float4 tv = *(const float4*)&ts[w][k];
        a2 = fmaf(tv.x, w2[(k + 0) * H + c], a2);
        a2 = fmaf(tv.y, w2[(k + 1) * H + c], a2);
        a2 = fmaf(tv.z, w2[(k + 2) * H + c], a2);
        a2 = fmaf(tv.w, w2[(k + 3) * H + c], a2);
    }
    float vnew = vn[(size_t)g * H + c] + a2;
    vn[(size_t)g * H + c] = vnew;
    ps[w][c] = vnew;
    float vlo = ps[w][(c & 31) * 2 + 0];
    float vhi = ps[w][(c & 31) * 2 + 1];
    int ch2 = (c & 31) * 2;
    for (n = s; n + 2 <= e; n += 2) {
        size_t off = (size_t)(n + (c >> 5)) * H + ch2;
        uint u = *(uint*)(h + off);
        float lo = bf2f(u) + vlo;
        float hi = bf2f(u >> 16) + vhi;
        *(uint*)(h + off) = f2bf(lo) | (f2bf(hi) << 16);
    }
    if (n < e && c < 32) {
        size_t off = (size_t)n * H + ch2;
        uint u = *(uint*)(h + off);
        float lo = bf2f(u) + vlo;
        float hi = bf2f(u >> 16) + vhi;
        *(uint*)(h + off) = f2bf(lo) | (f2bf(hi) << 16);
    }
}

// ---------------- final: mean pool, pep MLP, classifier ----------------
__global__ __launch_bounds__(256) void k_final(const float* __restrict__ pooled,
                                               const int* __restrict__ gstart,
                                               const float* __restrict__ pep,
                                               const float* __restrict__ pw, const float* __restrict__ pb,
                                               const float* __restrict__ cw1, const float* __restrict__ cb1,
                                               const float* __restrict__ cw2, const float* __restrict__ cb2,
                                               float* __restrict__ out) {
    __shared__ float red[4][H];
    __shared__ float fused[2 * H];
    int g = blockIdx.x;
    int lane = threadIdx.x & 63;
    int part = threadIdx.x >> 6;
    const float* pr = pep + (size_t)g * PEP_DIM;
    float acc = 0.0f;
    int k0 = part * (PEP_DIM / 4);
    for (int k = k0; k < k0 + PEP_DIM / 4; k++) {
        acc += pr[k] * pw[k * H + lane];
    }
    red[part][lane] = acc;
    __syncthreads();
    if (part == 0) {
        float s = red[0][lane] + red[1][lane] + red[2][lane] + red[3][lane] + pb[lane];
        fused[H + lane] = fmaxf(s, 0.0f);
        float c = (float)(gstart[g + 1] - gstart[g]);
        float invc = 1.0f / fmaxf(c, 1.0f);
        fused[lane] = pooled[(size_t)g * H + lane] * invc;
    }
    __syncthreads();
    if (part == 0) {
        float a = cb1[lane];
        for (int k = 0; k < 2 * H; k++) a += fused[k] * cw1[k * H + lane];
        float t = fmaxf(a, 0.0f);
        float v = t * cw2[lane];
        for (int off = 32; off > 0; off >>= 1) v += __shfl_down(v, off, 64);
        if (lane == 0) out[g] = v + cb2[0];
    }
}

extern "C" void kernel_launch(void* const* d_in, const int* in_sizes, int n_in,
                              void* d_out, int out_size, void* d_ws, size_t ws_size,
                              hipStream_t stream) {
    const float* x        = (const float*)d_in[0];
    const int*   ei       = (const int*)d_in[1];
    const int*   batch    = (const int*)d_in[2];
    const float* ea       = (const float*)d_in[3];
    const float* pep      = (const float*)d_in[4];
    const float* in_w     = (const float*)d_in[5];
    const float* in_b     = (const float*)d_in[6];
    const float* e_w      = (const float*)d_in[7];
    const float* e_b      = (const float*)d_in[8];
    const float* conv_w1  = (const float*)d_in[9];
    const float* conv_b1  = (const float*)d_in[10];
    const float* conv_w2  = (const float*)d_in[11];
    const float* conv_b2  = (const float*)d_in[12];
    const float* bn_w     = (const float*)d_in[13];
    const float* bn_b     = (const float*)d_in[14];
    const float* bn_mean  = (const float*)d_in[15];
    const float* bn_var   = (const float*)d_in[16];
    const float* vn_w1    = (const float*)d_in[17];
    const float* vn_b1    = (const float*)d_in[18];
    const float* vn_w2    = (const float*)d_in[19];
    const float* vn_b2    = (const float*)d_in[20];
    const float* pep_w    = (const float*)d_in[21];
    const float* pep_b    = (const float*)d_in[22];
    const float* cls_w1   = (const float*)d_in[23];
    const float* cls_b1   = (const float*)d_in[24];
    const float* cls_w2   = (const float*)d_in[25];
    const float* cls_b2   = (const float*)d_in[26];
    float* out = (float*)d_out;

    // ---- workspace layout (16B alignment maintained) ----
    ushort* h_a   = (ushort*)d_ws;                    // NN*H bf16
    ushort* h_b   = h_a + (size_t)NN * H;             // NN*H bf16
    ushort* z     = h_b + (size_t)NN * H;             // NN*H bf16 (aliased as tmp during CSR build)
    int2*  tmp    = (int2*)z;                         // NE int2 == NN*H*2B, disjoint lifetime
    float* pooled = (float*)(z + (size_t)NN * H);     // NG*H
    float* vn     = pooled + (size_t)NG * H;          // NG*H
    int2*  csr    = (int2*)(vn + (size_t)NG * H);     // NE (8B each)
    ushort* wp    = (ushort*)(csr + (size_t)NE);      // 3*8192 bf16 packed weights
    int* row_start = (int*)(wp + 3 * 8192);           // NN+16
    int* gstart    = row_start + NN + 16;             // NG+16
    int* mat       = gstart + NG + 16;                // NBUCK*NBLKA
    int* tot       = mat + NBUCK * NBLKA;             // NBUCK
    int* bases     = tot + NBUCK;                     // NBUCK+1

    // ---- build CSR via bucket sort (once; reused by all 3 layers) ----
    k_hist<<<NBLKA, 256, 0, stream>>>(ei, mat);
    k_s1<<<NBUCK, NBLKA, 0, stream>>>(mat, tot);
    k_s2<<<1, 256, 0, stream>>>(tot, bases);
    k_scat1<<<NBLKA, 256, 0, stream>>>(ei, ea, mat, bases, tmp);
    k_scat2<<<NBUCK, 256, 0, stream>>>(tmp, bases, csr, row_start);
    k_gstart<<<(NN + 255) / 256, 256, 0, stream>>>(batch, gstart);
    k_prep<<<(3 * 8192 + 255) / 256, 256, 0, stream>>>(conv_w1, conv_w2, wp);

    // ---- init ----
    k_init_h<<<NN * 16 / 256, 256, 0, stream>>>(x, in_w, in_b, h_a);
    hipMemsetAsync(vn, 0, (size_t)NG * H * sizeof(float), stream);

    ushort* hc = h_a;
    ushort* hn = h_b;
    for (int i = 0; i < 3; i++) {
        k_gather<<<GATHER_BLOCKS, 1024, 0, stream>>>(hc, z, csr, row_start, e_w, e_b);
        k_mlp<<<(NN + 63) / 64, 256, 0, stream>>>(z, hn, wp + i * 8192,
                                                  conv_b1 + i * H, conv_b2 + i * H,
                                                  bn_w + i * H, bn_b + i * H,
                                                  bn_mean + i * H, bn_var + i * H);
        ushort* t = hc; hc = hn; hn = t;   // hc now holds layer output
        k_poolvn<<<NG / 4, 256, 0, stream>>>(hc, gstart, pooled,
                                             vn_w1, vn_b1, vn_w2, vn_b2, vn,
                                             (i < 2) ? 1 : 0);
    }

    k_final<<<NG, 256, 0, stream>>>(pooled, gstart, pep, pep_w, pep_b,
                                    cls_w1, cls_b1, cls_w2, cls_b2, out);
}